// Round 9
// baseline (139.738 us; speedup 1.0000x reference)
//
#include <hip/hip_runtime.h>
#include <stdint.h>

// BATCH=4096, LENGTH=128, FEAT=4, RANK=64, 126 mid sites.
#define NSITES 126
#define XPITCH 516                 // xbuf row pitch (floats)
#define VPH    72                  // vbuf row pitch (halfs): 144B rows -> c*VPH
                                   // half8 reads 16B-aligned, 8 word-accesses/bank

typedef _Float16 half8_t  __attribute__((ext_vector_type(8)));
typedef float    float4_t __attribute__((ext_vector_type(4)));

// light barrier: LDS-only drain; asm G-loads (vmcnt) stay in flight across it
#define LBAR() asm volatile("s_waitcnt lgkmcnt(0)\n\ts_barrier" ::: "memory")
// explicit wait: oldest loads complete when <=N remain outstanding
#define WAITV(N) asm volatile("s_waitcnt vmcnt(" #N ")" ::: "memory")
// zero-instruction tie: forces the 8 frag values through a volatile asm node,
// so MFMAs (pure ops) cannot be scheduled above the preceding WAITV
#define TIE8(F) asm volatile("" : "+v"(F[0]), "+v"(F[1]), "+v"(F[2]), "+v"(F[3]), \
                                  "+v"(F[4]), "+v"(F[5]), "+v"(F[6]), "+v"(F[7]))

// volatile asm load — R0's thrice-proven form: full 64-bit VGPR address pair.
__device__ __forceinline__ void aload(half8_t& d, const void* p) {
    asm volatile("global_load_dwordx4 %0, %1, off" : "=v"(d) : "v"(p));
}

// grid-barrier ticket counter: __device__ global (.bss, zero at module load),
// monotonically increasing across launches/replays -> needs no per-launch
// reset. One atomicAdd per BLOCK per launch => launch n starts at 256*n, so
// a block with ticket t waits until the counter reaches (t/256+1)*256.
__device__ unsigned long long g_bar;

// ---------------------------------------------------------------------------
// Fused kernel: 256 blocks x 256 threads (1 block/CU => all blocks
// co-resident by capacity; manual spin barrier is deadlock-free).
//  phase 1: repack mid fp32 [126][64][4][64] -> fp16 frags (grid-stride).
//           Frag F (16B): elem j = G[l=32h+8q+j][n=i*64+w*16+c], lane=16q+c,
//           F = ((i*2+h)*4+w)*64 + lane (+ s*2048). HW-verified R0/R3/R7/R8.
//  phase 2a: x-stage + v0 prologue (block-local; overlaps repack tail).
//  grid barrier: threadfence (agent release: gt visible cross-XCD) + ticket
//           spin. (Even a stale-L2 read would be benign: gt = f(mid) is
//           deterministic, so re-written values are bit-identical.)
//  phase 2b: R8's chain VERBATIM — 4 waves, wave w owns r-cols [16w,16w+16),
//           G in VGPRs via 2-site asm prefetch pipeline, WAITV(16)+TIE8,
//           fp16 vbuf, one lgkm-only barrier per site.
// ---------------------------------------------------------------------------
__global__ __launch_bounds__(256) void fused(
    const float* __restrict__ x,      // [4096][128][4]
    const float* __restrict__ first,  // [4][64]
    const float* __restrict__ last,   // [64][4]
    const float* __restrict__ mid,    // [126][64][4][64]
    _Float16* __restrict__ gt,        // frag-ordered fp16, 32 KB/site
    float* __restrict__ out) {        // [4096]

    __shared__ __align__(16) _Float16 vbuf[2][16 * VPH];
    __shared__ float xbuf[16 * XPITCH];
    __shared__ int   eacc[16];

    const int tid  = threadIdx.x;
    const int w    = tid >> 6;
    const int lane = tid & 63;
    const int q    = lane >> 4;
    const int c    = lane & 15;
    const int b0   = blockIdx.x * 16;

    // ---- phase 1: repack (grid-stride over 126*2048 fragments) ----
    for (int F = blockIdx.x * 256 + tid; F < NSITES * 2048; F += 256 * 256) {
        const int fl = F & 63, fw = (F >> 6) & 3, fh = (F >> 8) & 1, fi = (F >> 9) & 3;
        const int fs = F >> 11;
        const int fq = fl >> 4, fc = fl & 15;
        const float* src = mid + (size_t)fs * 16384 + (32 * fh + 8 * fq) * 256 + fi * 64 + fw * 16 + fc;
        half8_t o;
#pragma unroll
        for (int j = 0; j < 8; ++j) o[j] = (_Float16)src[j * 256];
        ((half8_t*)gt)[F] = o;
    }

    // ---- phase 2a: stage x (16 rows x 512 floats, coalesced) ----
    {
        const int bb = tid >> 4, seg = tid & 15;
        const float4_t* src = (const float4_t*)(x + (size_t)(b0 + bb) * 512 + seg * 32);
        float4_t* dst = (float4_t*)(xbuf + bb * XPITCH + seg * 32);
#pragma unroll
        for (int k = 0; k < 8; ++k) dst[k] = src[k];
    }
    if (tid < 16) eacc[tid] = 0;
    __syncthreads();

    // v0[b,r] = sum_i x[b,0,i] * first[i,r]  (fp16 store)
    {
        const int bb = tid >> 4, rq = tid & 15;
        const float xs0 = xbuf[bb * XPITCH + 0], xs1 = xbuf[bb * XPITCH + 1];
        const float xs2 = xbuf[bb * XPITCH + 2], xs3 = xbuf[bb * XPITCH + 3];
#pragma unroll
        for (int k = 0; k < 4; ++k) {
            const int r = rq * 4 + k;
            vbuf[0][bb * VPH + r] = (_Float16)(
                xs0 * first[r] + xs1 * first[64 + r] + xs2 * first[128 + r] + xs3 * first[192 + r]);
        }
    }

    // ---- grid barrier (ticket scheme; one arrival per block) ----
    __syncthreads();
    if (tid == 0) {
        __threadfence();   // agent-scope release: repack writes visible device-wide
        const unsigned long long my = atomicAdd(&g_bar, 1ull);
        const unsigned long long target = (my / 256 + 1) * 256;
        while (__hip_atomic_load(&g_bar, __ATOMIC_ACQUIRE, __HIP_MEMORY_SCOPE_AGENT) < target)
            __builtin_amdgcn_s_sleep(8);
        __threadfence();
    }
    __syncthreads();

    // ---- phase 2b: chain (verbatim R8) ----
    half8_t F0[8], F1[8], F2[8];
    const char* gbase = (const char*)gt + w * 1024 + lane * 16;
    auto LOAD = [&](int s, half8_t* F) {
        const char* p = gbase + (size_t)s * 32768;
#pragma unroll
        for (int ih = 0; ih < 8; ++ih) aload(F[ih], p + ih * 4096);
    };
    LOAD(0, F0);    // outstanding: 8
    LOAD(1, F1);    // outstanding: 16
    LBAR();         // vbuf[0] visible (lgkm only; G loads stay in flight)

    auto STEP = [&](int s, half8_t* F) {
        const int p = s & 1;

        // A-frags + x issued BEFORE the G-wait: depend only on the previous
        // site's LBAR, so their LDS latency hides under WAITV(16).
        const _Float16* vr = &vbuf[p][c * VPH];
        half8_t af0 = *(const half8_t*)(vr + q * 8);          // v[c][8q..8q+7]
        half8_t af1 = *(const half8_t*)(vr + 32 + q * 8);     // v[c][32+8q..]
        float4_t xs[4];
#pragma unroll
        for (int jj = 0; jj < 4; ++jj)
            xs[jj] = *(const float4_t*)(xbuf + (q * 4 + jj) * XPITCH + (s + 1) * 4);

        // invariant: 24 outstanding here; oldest 8 = this site's frags
        WAITV(16);
        TIE8(F);

        // wave-local per-batch power-of-2 renorm every 8 sites (f32 unpack)
        if ((s & 7) == 0 && s != 0) {
            float a[16];
#pragma unroll
            for (int k = 0; k < 8; ++k) { a[k] = (float)af0[k]; a[8 + k] = (float)af1[k]; }
            float m = 0.f;
#pragma unroll
            for (int k = 0; k < 16; ++k) m = fmaxf(m, fabsf(a[k]));
            m = fmaxf(m, __shfl_xor(m, 16));   // max over q: all 64 r per batch
            m = fmaxf(m, __shfl_xor(m, 32));
            int e = 0;
            if (m > 0.f) frexpf(m, &e);
            const float sc = ldexpf(1.0f, -e);
#pragma unroll
            for (int k = 0; k < 8; ++k) {
                af0[k] = (_Float16)(a[k] * sc);
                af1[k] = (_Float16)(a[8 + k] * sc);
            }
            if (tid < 16) eacc[tid] += e;   // wave 0, q=0: lane==c==batch
        }

        float4_t acc[4];
#pragma unroll
        for (int i = 0; i < 4; ++i) {
            float4_t z = {0.f, 0.f, 0.f, 0.f};
            z = __builtin_amdgcn_mfma_f32_16x16x32_f16(af0, F[i * 2 + 0], z, 0, 0, 0);
            z = __builtin_amdgcn_mfma_f32_16x16x32_f16(af1, F[i * 2 + 1], z, 0, 0, 0);
            acc[i] = z;
        }

#pragma unroll
        for (int jj = 0; jj < 4; ++jj) {
            const float vn = xs[jj].x * acc[0][jj] + xs[jj].y * acc[1][jj] +
                             xs[jj].z * acc[2][jj] + xs[jj].w * acc[3][jj];
            vbuf[p ^ 1][(q * 4 + jj) * VPH + w * 16 + c] = (_Float16)vn;
        }
        LBAR();
    };

    for (int s = 0; s < NSITES; s += 3) {
        const int s2 = (s + 2 < NSITES) ? s + 2 : NSITES - 1;
        const int s3 = (s + 3 < NSITES) ? s + 3 : NSITES - 1;
        const int s4 = (s + 4 < NSITES) ? s + 4 : NSITES - 1;
        LOAD(s2, F2);          // every STEP is preceded by exactly one 8-load
        STEP(s, F0);           // LOAD -> WAITV(16) invariant holds throughout
        LOAD(s3, F0);
        STEP(s + 1, F1);
        LOAD(s4, F1);
        STEP(s + 2, F2);
    }
    WAITV(0);   // drain tail (clamped re-loads of site 125)

    // final v in vbuf[0] (126 even); out[b] = 2^eacc * sum_r v*last_vec
    {
        const int bb = tid >> 4, rq = tid & 15;
        const float x0 = xbuf[bb * XPITCH + 508], x1 = xbuf[bb * XPITCH + 509];
        const float x2 = xbuf[bb * XPITCH + 510], x3 = xbuf[bb * XPITCH + 511];
        float dot = 0.f;
#pragma unroll
        for (int k = 0; k < 4; ++k) {
            const int r = rq * 4 + k;
            const float lv = last[r * 4 + 0] * x0 + last[r * 4 + 1] * x1 +
                             last[r * 4 + 2] * x2 + last[r * 4 + 3] * x3;
            dot += lv * (float)vbuf[0][bb * VPH + r];
        }
#pragma unroll
        for (int o = 8; o > 0; o >>= 1) dot += __shfl_xor(dot, o, 16);
        if (rq == 0) out[b0 + bb] = ldexpf(dot, eacc[bb]);
    }
}

extern "C" void kernel_launch(void* const* d_in, const int* in_sizes, int n_in,
                              void* d_out, int out_size, void* d_ws, size_t ws_size,
                              hipStream_t stream) {
    (void)in_sizes; (void)n_in; (void)out_size; (void)ws_size;
    const float* x     = (const float*)d_in[0];
    const float* first = (const float*)d_in[1];
    const float* mid   = (const float*)d_in[2];
    const float* last  = (const float*)d_in[3];
    float* out = (float*)d_out;
    _Float16* gt = (_Float16*)d_ws;   // 126*2048*16 B = 4,128,768 B

    fused<<<256, 256, 0, stream>>>(x, first, last, mid, gt, out);
}

// Round 10
// 127.786 us; speedup vs baseline: 1.0935x; 1.0935x over previous
//
#include <hip/hip_runtime.h>
#include <stdint.h>

// BATCH=4096, LENGTH=128, FEAT=4, RANK=64, 126 mid sites.
#define NSITES 126
#define XPITCH 516                 // xbuf row pitch (floats)
#define VPF    68                  // pbuf row pitch (floats): 272B rows; af b128
                                   // reads land 8 words/bank (uniform), writes 2-way

typedef _Float16 half8_t  __attribute__((ext_vector_type(8)));
typedef float    float4_t __attribute__((ext_vector_type(4)));

// light barrier: LDS-only drain; asm G-loads (vmcnt) stay in flight across it
#define LBAR() asm volatile("s_waitcnt lgkmcnt(0)\n\ts_barrier" ::: "memory")
// explicit wait: oldest loads complete when <=N remain outstanding
#define WAITV(N) asm volatile("s_waitcnt vmcnt(" #N ")" ::: "memory")
// zero-instruction tie: forces the 4 frag values through a volatile asm node,
// so MFMAs (pure ops) cannot be scheduled above the preceding WAITV
#define TIE4(F) asm volatile("" : "+v"(F[0]), "+v"(F[1]), "+v"(F[2]), "+v"(F[3]))

// volatile asm load — R0's thrice-proven form: full 64-bit VGPR address pair.
__device__ __forceinline__ void aload(half8_t& d, const void* p) {
    asm volatile("global_load_dwordx4 %0, %1, off" : "=v"(d) : "v"(p));
}

// ---------------------------------------------------------------------------
// Repack mid_cores fp32 [126][64][4][64] -> fp16 fragments, frag F (16B):
// element j = G[l = 32h + 8q + j][n = i*64 + w*16 + c], lane = 16q + c,
// F = ((i*2+h)*4 + w)*64 + lane  (+ s*2048). HW-verified (R0/R3/R7/R8/R9).
// Separate launch: costs ~6 µs total (R8/R9 decomposition); fusing it costs 25.
// ---------------------------------------------------------------------------
__global__ __launch_bounds__(256) void repack_g(const float* __restrict__ mid,
                                                _Float16* __restrict__ gt) {
    const int F = blockIdx.x * 256 + threadIdx.x;          // 0..258047 == 126*2048
    const int lane = F & 63, w = (F >> 6) & 3, h = (F >> 8) & 1, i = (F >> 9) & 3;
    const int s = F >> 11;
    const int q = lane >> 4, c = lane & 15;
    const float* src = mid + (size_t)s * 16384 + (32 * h + 8 * q) * 256 + i * 64 + w * 16 + c;
    half8_t o;
#pragma unroll
    for (int j = 0; j < 8; ++j) o[j] = (_Float16)src[j * 256];
    ((half8_t*)gt)[F] = o;
}

// ---------------------------------------------------------------------------
// Main chain: 256 blocks x 512 threads (1 block/CU, 16 batches/CU, 8 waves =
// 2 waves/SIMD). k-SPLIT: wave w = (wv = w&3, h = w>>2) owns r-cols
// [16wv,16wv+16) and k-half [32h,32h+32). Its 4 frags/site (f=0..3 at index
// f*2+h) are DISJOINT across waves -> per-CU G traffic stays 32KB/site while
// 2 waves/SIMD hide each other's latency (R8's 70% exposed-wait problem).
// Per site per wave: af = (half)(pbuf[0]+pbuf[1])[c][32h+8q..], 4 MFMAs,
// partial[jj] = sum_f x_f*acc_f, write f32 to pbuf[h]. One LBAR per site.
// Renorm: measure half-max at s%8==7 into hmf, apply bound 2*max(hm0,hm1)
// at s%8==0 — power-of-2 exact, so output is bit-identical to R8.
// ---------------------------------------------------------------------------
__global__ __launch_bounds__(512, 1) void tt_chain(
    const float* __restrict__ x,      // [4096][128][4]
    const float* __restrict__ first,  // [4][64]
    const float* __restrict__ last,   // [64][4]
    const _Float16* __restrict__ gt,  // frag-ordered fp16, 32 KB/site
    float* __restrict__ out) {        // [4096]

    __shared__ float xbuf[16 * XPITCH];
    __shared__ __align__(16) float pbuf[2][2][16 * VPF];   // [parity][h][batch*VPF + r]
    __shared__ float hmf[2][16];
    __shared__ int   eacc[16];

    const int tid  = threadIdx.x;
    const int w    = tid >> 6;        // 0..7
    const int wv   = w & 3;           // r-col group
    const int h    = w >> 2;          // k-half
    const int lane = tid & 63;
    const int q    = lane >> 4;
    const int c    = lane & 15;
    const int b0   = blockIdx.x * 16;

    // stage x: 16 rows x 512 floats, coalesced (512 threads)
    {
        const int bb = tid >> 5, seg = tid & 31;
        const float4_t* src = (const float4_t*)(x + (size_t)(b0 + bb) * 512);
        float4_t* dst = (float4_t*)(xbuf + bb * XPITCH);
#pragma unroll
        for (int k = 0; k < 4; ++k) dst[seg + 32 * k] = src[seg + 32 * k];
    }
    if (tid < 16) eacc[tid] = 0;
    __syncthreads();

    // v0[b,r] = sum_i x[b,0,i]*first[i,r]  (f32; half h=0 carries v0, h=1 zero)
    if (tid < 256) {
        const int bb = tid >> 4, rq = tid & 15;
        const float xs0 = xbuf[bb * XPITCH + 0], xs1 = xbuf[bb * XPITCH + 1];
        const float xs2 = xbuf[bb * XPITCH + 2], xs3 = xbuf[bb * XPITCH + 3];
#pragma unroll
        for (int k = 0; k < 4; ++k) {
            const int r = rq * 4 + k;
            pbuf[0][0][bb * VPF + r] =
                xs0 * first[r] + xs1 * first[64 + r] + xs2 * first[128 + r] + xs3 * first[192 + r];
            pbuf[0][1][bb * VPF + r] = 0.f;
        }
    }

    // G register pipeline: per wave 4 frags/site at byte offset
    // s*32768 + f*8192 + h*4096 + wv*1024 + lane*16
    half8_t F0[4], F1[4], F2[4];
    const char* gbase = (const char*)gt + h * 4096 + wv * 1024 + lane * 16;
    auto LOAD = [&](int s, half8_t* F) {
        const char* p = gbase + (size_t)s * 32768;
#pragma unroll
        for (int f = 0; f < 4; ++f) aload(F[f], p + f * 8192);
    };
    LOAD(0, F0);    // outstanding: 4
    LOAD(1, F1);    // outstanding: 8
    LBAR();         // pbuf[0] visible (lgkm only; G loads stay in flight)

    auto STEP = [&](int s, half8_t* F) {
        const int p = s & 1;

        // A-half prep + x reads BEFORE the G-wait (depend only on prev LBAR):
        // v[c][32h+8q+j] = pbuf[p][0][..] + pbuf[p][1][..]
        const float* r0 = &pbuf[p][0][c * VPF + 32 * h + 8 * q];
        const float* r1 = &pbuf[p][1][c * VPF + 32 * h + 8 * q];
        float4_t alo = *(const float4_t*)r0 + *(const float4_t*)r1;
        float4_t ahi = *(const float4_t*)(r0 + 4) + *(const float4_t*)(r1 + 4);
        float4_t xs[4];
#pragma unroll
        for (int jj = 0; jj < 4; ++jj)
            xs[jj] = *(const float4_t*)(xbuf + (q * 4 + jj) * XPITCH + (s + 1) * 4);

        // apply renorm (e from bound measured at s-1; power-of-2 exact)
        if ((s & 7) == 0 && s != 0) {
            const float mx = 2.0f * fmaxf(hmf[0][c], hmf[1][c]);
            int e = 0;
            if (mx > 0.f) frexpf(mx, &e);
            const float sc = ldexpf(1.0f, -e);
#pragma unroll
            for (int k = 0; k < 4; ++k) { alo[k] *= sc; ahi[k] *= sc; }
            if (w == 0 && lane < 16) eacc[lane] += e;   // all waves compute same e
        }
        // measure half-max for the next apply site (visible after this LBAR)
        if ((s & 7) == 7 && s < 120) {
            float hl = 0.f;
#pragma unroll
            for (int k = 0; k < 4; ++k)
                hl = fmaxf(hl, fmaxf(fabsf(alo[k]), fabsf(ahi[k])));
            hl = fmaxf(hl, __shfl_xor(hl, 16));   // max over q: this half's 32 r's
            hl = fmaxf(hl, __shfl_xor(hl, 32));
            if (wv == 0 && q == 0) hmf[h][c] = hl;
        }

        half8_t af;
#pragma unroll
        for (int k = 0; k < 4; ++k) { af[k] = (_Float16)alo[k]; af[4 + k] = (_Float16)ahi[k]; }

        // invariant: 12 outstanding here; oldest 4 = this site's frags
        WAITV(8);
        TIE4(F);

        float4_t acc[4];
#pragma unroll
        for (int f = 0; f < 4; ++f) {
            float4_t z = {0.f, 0.f, 0.f, 0.f};
            acc[f] = __builtin_amdgcn_mfma_f32_16x16x32_f16(af, F[f], z, 0, 0, 0);
        }

        // partial combine for this k-half; D row=4q+jj (batch), col=wv*16+c (r')
        float* pw = &pbuf[p ^ 1][h][0];
#pragma unroll
        for (int jj = 0; jj < 4; ++jj) {
            const float vn = xs[jj][0] * acc[0][jj] + xs[jj][1] * acc[1][jj] +
                             xs[jj][2] * acc[2][jj] + xs[jj][3] * acc[3][jj];
            pw[(q * 4 + jj) * VPF + wv * 16 + c] = vn;
        }
        LBAR();
    };

    for (int s = 0; s < NSITES; s += 3) {
        const int s2 = (s + 2 < NSITES) ? s + 2 : NSITES - 1;
        const int s3 = (s + 3 < NSITES) ? s + 3 : NSITES - 1;
        const int s4 = (s + 4 < NSITES) ? s + 4 : NSITES - 1;
        LOAD(s2, F2);          // every STEP is preceded by exactly one 4-load
        STEP(s, F0);           // LOAD -> WAITV(8) invariant holds throughout
        LOAD(s3, F0);
        STEP(s + 1, F1);
        LOAD(s4, F1);
        STEP(s + 2, F2);
    }
    WAITV(0);   // drain tail (clamped re-loads of site 125)

    // final v in pbuf[0] (126 even): v = p0 + p1; out[b] = 2^eacc * v.last_vec
    if (tid < 256) {
        const int bb = tid >> 4, rq = tid & 15;
        const float x0 = xbuf[bb * XPITCH + 508], x1 = xbuf[bb * XPITCH + 509];
        const float x2 = xbuf[bb * XPITCH + 510], x3 = xbuf[bb * XPITCH + 511];
        float dot = 0.f;
#pragma unroll
        for (int k = 0; k < 4; ++k) {
            const int r = rq * 4 + k;
            const float lv = last[r * 4 + 0] * x0 + last[r * 4 + 1] * x1 +
                             last[r * 4 + 2] * x2 + last[r * 4 + 3] * x3;
            const float v = pbuf[0][0][bb * VPF + r] + pbuf[0][1][bb * VPF + r];
            dot += lv * v;
        }
#pragma unroll
        for (int o = 8; o > 0; o >>= 1) dot += __shfl_xor(dot, o, 16);
        if (rq == 0) out[b0 + bb] = ldexpf(dot, eacc[bb]);
    }
}

extern "C" void kernel_launch(void* const* d_in, const int* in_sizes, int n_in,
                              void* d_out, int out_size, void* d_ws, size_t ws_size,
                              hipStream_t stream) {
    (void)in_sizes; (void)n_in; (void)out_size; (void)ws_size;
    const float* x     = (const float*)d_in[0];
    const float* first = (const float*)d_in[1];
    const float* mid   = (const float*)d_in[2];
    const float* last  = (const float*)d_in[3];
    float* out = (float*)d_out;
    _Float16* gt = (_Float16*)d_ws;   // 126*2048*16 B = 4,128,768 B

    repack_g<<<1008, 256, 0, stream>>>(mid, gt);
    tt_chain<<<256, 512, 0, stream>>>(x, first, last, gt, out);
}

// Round 11
// 111.370 us; speedup vs baseline: 1.2547x; 1.1474x over previous
//
#include <hip/hip_runtime.h>
#include <stdint.h>

// BATCH=4096, LENGTH=128, FEAT=4, RANK=64, 126 mid sites.
#define NSITES 126
#define XPITCH 516                 // xbuf row pitch (floats)
#define VPH    72                  // vbuf row pitch (halfs): 144B rows

typedef _Float16 half8_t  __attribute__((ext_vector_type(8)));
typedef float    float4_t __attribute__((ext_vector_type(4)));

// light barrier: LDS-only drain; asm G-loads (vmcnt) stay in flight across it
#define LBAR() asm volatile("s_waitcnt lgkmcnt(0)\n\ts_barrier" ::: "memory")
// explicit wait: oldest loads complete when <=N remain outstanding
#define WAITV(N) asm volatile("s_waitcnt vmcnt(" #N ")" ::: "memory")
// zero-instruction tie: forces the 8 frag values through a volatile asm node,
// so MFMAs (pure ops) cannot be scheduled above the preceding WAITV
#define TIE8(F) asm volatile("" : "+v"(F[0]), "+v"(F[1]), "+v"(F[2]), "+v"(F[3]), \
                                  "+v"(F[4]), "+v"(F[5]), "+v"(F[6]), "+v"(F[7]))

// volatile asm load — R0's thrice-proven form: full 64-bit VGPR address pair.
__device__ __forceinline__ void aload(half8_t& d, const void* p) {
    asm volatile("global_load_dwordx4 %0, %1, off" : "=v"(d) : "v"(p));
}

// ---------------------------------------------------------------------------
// Repack mid_cores fp32 [126][64][4][64] -> fp16 fragments, frag F (16B):
// element j = G[l = 32h + 8q + j][n = i*64 + w*16 + c], lane = 16q + c,
// F = ((i*2+h)*4 + w)*64 + lane  (+ s*2048). HW-verified (R0/R3/R7/R8/R9/R10).
// ---------------------------------------------------------------------------
__global__ __launch_bounds__(256) void repack_g(const float* __restrict__ mid,
                                                _Float16* __restrict__ gt) {
    const int F = blockIdx.x * 256 + threadIdx.x;          // 0..258047 == 126*2048
    const int lane = F & 63, w = (F >> 6) & 3, h = (F >> 8) & 1, i = (F >> 9) & 3;
    const int s = F >> 11;
    const int q = lane >> 4, c = lane & 15;
    const float* src = mid + (size_t)s * 16384 + (32 * h + 8 * q) * 256 + i * 64 + w * 16 + c;
    half8_t o;
#pragma unroll
    for (int j = 0; j < 8; ++j) o[j] = (_Float16)src[j * 256];
    ((half8_t*)gt)[F] = o;
}

// ---------------------------------------------------------------------------
// Main chain: 256 blocks x 512 threads (1 block/CU, 16 batches/CU, 8 waves =
// 2 teams of 4). Team T = w>>2 runs STEP for sites s%2==T (its wave wv = w&3
// owns r-cols [16wv,16wv+16) — internals byte-for-byte R8); on off-windows it
// runs PREP: its next stride-2 G 8-load + xs pre-read into registers. One
// LBAR per site for all 8 waves. Per-CU G traffic unchanged (each site loaded
// by exactly one team). Active window = pure critical chain (af read -> MFMA
// -> combine -> write); prep issue cycles run concurrently on the other
// SIMD slots. Per-team ledger: 3 rotating 8-frag buffers, 24 outstanding at
// each WAITV(16) (stride-2 mirror of R8's invariant).
// ---------------------------------------------------------------------------
__global__ __launch_bounds__(512, 2) void tt_chain(
    const float* __restrict__ x,      // [4096][128][4]
    const float* __restrict__ first,  // [4][64]
    const float* __restrict__ last,   // [64][4]
    const _Float16* __restrict__ gt,  // frag-ordered fp16, 32 KB/site
    float* __restrict__ out) {        // [4096]

    __shared__ __align__(16) _Float16 vbuf[2][16 * VPH];
    __shared__ float xbuf[16 * XPITCH];
    __shared__ int   eacc[16];

    const int tid  = threadIdx.x;
    const int w    = tid >> 6;        // 0..7
    const int team = w >> 2;          // 0: even sites, 1: odd sites
    const int wv   = w & 3;           // r-col group within team
    const int lane = tid & 63;
    const int q    = lane >> 4;
    const int c    = lane & 15;
    const int b0   = blockIdx.x * 16;

    // stage x: 16 rows x 512 floats, coalesced across 512 threads
    {
        const int bb = tid >> 5, seg = tid & 31;
        const float4_t* src = (const float4_t*)(x + (size_t)(b0 + bb) * 512);
        float4_t* dst = (float4_t*)(xbuf + bb * XPITCH);
#pragma unroll
        for (int k = 0; k < 4; ++k) dst[seg + 32 * k] = src[seg + 32 * k];
    }
    if (tid < 16) eacc[tid] = 0;
    __syncthreads();

    // v0[b,r] = sum_i x[b,0,i] * first[i,r]  (fp16 store) — verbatim R8
    if (tid < 256) {
        const int bb = tid >> 4, rq = tid & 15;
        const float xs0 = xbuf[bb * XPITCH + 0], xs1 = xbuf[bb * XPITCH + 1];
        const float xs2 = xbuf[bb * XPITCH + 2], xs3 = xbuf[bb * XPITCH + 3];
#pragma unroll
        for (int k = 0; k < 4; ++k) {
            const int r = rq * 4 + k;
            vbuf[0][bb * VPH + r] = (_Float16)(
                xs0 * first[r] + xs1 * first[64 + r] + xs2 * first[128 + r] + xs3 * first[192 + r]);
        }
    }

    // per-team G pipeline: 8 frags/site at s*32768 + ih*4096 + wv*1024 + lane*16
    half8_t F0[8], F1[8], F2[8];
    const char* gbase = (const char*)gt + wv * 1024 + lane * 16;
    auto LOAD = [&](int s, half8_t* F) {
        const char* p = gbase + (size_t)s * 32768;
#pragma unroll
        for (int ih = 0; ih < 8; ++ih) aload(F[ih], p + ih * 4096);
    };

    // xs pre-read (persistent regs): for site s, col (s+1)*4
    float4_t xs[4];
    auto XRD = [&](int s) {
#pragma unroll
        for (int jj = 0; jj < 4; ++jj)
            xs[jj] = *(const float4_t*)(xbuf + (q * 4 + jj) * XPITCH + (s + 1) * 4);
    };

    // prologue: team0 {0,2,4} (24 out), team1 {1,3} (16 out; site 5 at w0)
    if (team == 0) { LOAD(0, F0); LOAD(2, F1); LOAD(4, F2); XRD(0); }
    else           { LOAD(1, F0); LOAD(3, F1); }
    LBAR();         // vbuf[0] visible (lgkm only; G loads stay in flight)

    // STEP internals — byte-for-byte R8 (minus xs read, pre-read in PREP)
    auto STEP = [&](int s, half8_t* F) {
        const int p = s & 1;
        const _Float16* vr = &vbuf[p][c * VPH];
        half8_t af0 = *(const half8_t*)(vr + q * 8);          // v[c][8q..8q+7]
        half8_t af1 = *(const half8_t*)(vr + 32 + q * 8);     // v[c][32+8q..]

        // invariant: 24 outstanding for this team; oldest 8 = this site's frags
        WAITV(16);
        TIE8(F);

        // wave-local per-batch power-of-2 renorm every 8 sites (team0 sites only)
        if ((s & 7) == 0 && s != 0) {
            float a[16];
#pragma unroll
            for (int k = 0; k < 8; ++k) { a[k] = (float)af0[k]; a[8 + k] = (float)af1[k]; }
            float m = 0.f;
#pragma unroll
            for (int k = 0; k < 16; ++k) m = fmaxf(m, fabsf(a[k]));
            m = fmaxf(m, __shfl_xor(m, 16));   // max over q: all 64 r per batch
            m = fmaxf(m, __shfl_xor(m, 32));
            int e = 0;
            if (m > 0.f) frexpf(m, &e);
            const float sc = ldexpf(1.0f, -e);
#pragma unroll
            for (int k = 0; k < 8; ++k) {
                af0[k] = (_Float16)(a[k] * sc);
                af1[k] = (_Float16)(a[8 + k] * sc);
            }
            if (tid < 16) eacc[tid] += e;   // wave 0 (team0), q=0: lane==c==batch
        }

        float4_t acc[4];
#pragma unroll
        for (int i = 0; i < 4; ++i) {
            float4_t z = {0.f, 0.f, 0.f, 0.f};
            z = __builtin_amdgcn_mfma_f32_16x16x32_f16(af0, F[i * 2 + 0], z, 0, 0, 0);
            z = __builtin_amdgcn_mfma_f32_16x16x32_f16(af1, F[i * 2 + 1], z, 0, 0, 0);
            acc[i] = z;
        }

#pragma unroll
        for (int jj = 0; jj < 4; ++jj) {
            const float vn = xs[jj].x * acc[0][jj] + xs[jj].y * acc[1][jj] +
                             xs[jj].z * acc[2][jj] + xs[jj].w * acc[3][jj];
            vbuf[p ^ 1][(q * 4 + jj) * VPH + wv * 16 + c] = (_Float16)vn;
        }
    };

    // 126 = 21 x 6 windows; per block of 6: team0 STEPs B,B+2,B+4 (F0,F1,F2),
    // team1 STEPs B+1,B+3,B+5. Off-team windows: one 8-LOAD + one XRD.
    // Clamped tail loads are in-bounds dups, drained by final WAITV(0).
    for (int B = 0; B < NSITES; B += 6) {
        // w0
        if (team == 0) STEP(B + 0, F0);
        else { LOAD((B + 5 < NSITES) ? B + 5 : 125, F2); XRD(B + 1); }
        LBAR();
        // w1
        if (team == 1) STEP(B + 1, F0);
        else { LOAD((B + 6 < NSITES) ? B + 6 : 124, F0); XRD(B + 2); }
        LBAR();
        // w2
        if (team == 0) STEP(B + 2, F1);
        else { LOAD((B + 7 < NSITES) ? B + 7 : 125, F0); XRD(B + 3); }
        LBAR();
        // w3
        if (team == 1) STEP(B + 3, F1);
        else { LOAD((B + 8 < NSITES) ? B + 8 : 124, F1); XRD(B + 4); }
        LBAR();
        // w4
        if (team == 0) STEP(B + 4, F2);
        else { LOAD((B + 9 < NSITES) ? B + 9 : 125, F1); XRD(B + 5); }
        LBAR();
        // w5
        if (team == 1) STEP(B + 5, F2);
        else { LOAD((B + 10 < NSITES) ? B + 10 : 124, F2); XRD(B + 6); }
        LBAR();
    }
    WAITV(0);   // drain tail dups

    // final v in vbuf[0] (126 even); out[b] = 2^eacc * sum_r v*last_vec — R8
    if (tid < 256) {
        const int bb = tid >> 4, rq = tid & 15;
        const float x0 = xbuf[bb * XPITCH + 508], x1 = xbuf[bb * XPITCH + 509];
        const float x2 = xbuf[bb * XPITCH + 510], x3 = xbuf[bb * XPITCH + 511];
        float dot = 0.f;
#pragma unroll
        for (int k = 0; k < 4; ++k) {
            const int r = rq * 4 + k;
            const float lv = last[r * 4 + 0] * x0 + last[r * 4 + 1] * x1 +
                             last[r * 4 + 2] * x2 + last[r * 4 + 3] * x3;
            dot += lv * (float)vbuf[0][bb * VPH + r];
        }
#pragma unroll
        for (int o = 8; o > 0; o >>= 1) dot += __shfl_xor(dot, o, 16);
        if (rq == 0) out[b0 + bb] = ldexpf(dot, eacc[bb]);
    }
}

extern "C" void kernel_launch(void* const* d_in, const int* in_sizes, int n_in,
                              void* d_out, int out_size, void* d_ws, size_t ws_size,
                              hipStream_t stream) {
    (void)in_sizes; (void)n_in; (void)out_size; (void)ws_size;
    const float* x     = (const float*)d_in[0];
    const float* first = (const float*)d_in[1];
    const float* mid   = (const float*)d_in[2];
    const float* last  = (const float*)d_in[3];
    float* out = (float*)d_out;
    _Float16* gt = (_Float16*)d_ws;   // 126*2048*16 B = 4,128,768 B

    repack_g<<<1008, 256, 0, stream>>>(mid, gt);
    tt_chain<<<256, 512, 0, stream>>>(x, first, last, gt, out);
}